// Round 1
// baseline (294.233 us; speedup 1.0000x reference)
//
#include <hip/hip_runtime.h>
#include <cstddef>
#include <cstdint>

// ---------------- problem constants ----------------
#define cB   512
#define cV   5023
#define cS   100
#define cE   50
#define cJ   5
#define cLD  17
#define cLS  51
#define cLF  68

#define cV3   15069        // V*3
#define cNPAD 15168        // 79*192, padded N
#define cKS   150          // shape+expr K
#define cKT   186          // + pose_feature (36)
#define cKPAD 192

#define OUT_V  ((size_t)cB * cV * 3)      // 7,715,328
#define OUT_L  ((size_t)cB * cLF * 3)     // 104,448

// ws layout (in floats)
#define WS_BT   ((size_t)0)                          // [192][15168]
#define WS_AT   (WS_BT + (size_t)cKPAD * cNPAD)      // [192][512]
#define WS_JS   (WS_AT + (size_t)cKPAD * cB)         // 2265 (+pad)
#define WS_AREL (WS_JS + 2272)                       // [512][60]
#define WS_PF   (WS_AREL + (size_t)cB * 60)          // [512][36]
#define WS_YROT (WS_PF + (size_t)cB * 36)            // 512 ints

// ---------------- rodrigues (matches jax reference exactly in fp32) ----------------
__device__ __forceinline__ void rodrigues9(float rx, float ry, float rz, float* R) {
  float a0 = rx + 1e-8f, a1 = ry + 1e-8f, a2 = rz + 1e-8f;
  float angle = sqrtf(a0 * a0 + a1 * a1 + a2 * a2);
  float inv = 1.0f / angle;
  float x = rx * inv, y = ry * inv, z = rz * inv;
  float s = sinf(angle), c = cosf(angle);
  float t = 1.0f - c;
  float xy = x * y, xz = x * z, yz = y * z;
  R[0] = 1.0f - t * (y * y + z * z);
  R[1] = -s * z + t * xy;
  R[2] =  s * y + t * xz;
  R[3] =  s * z + t * xy;
  R[4] = 1.0f - t * (x * x + z * z);
  R[5] = -s * x + t * yz;
  R[6] = -s * y + t * xz;
  R[7] =  s * x + t * yz;
  R[8] = 1.0f - t * (x * x + y * y);
}

// ---------------- k_js: JS[j,c,l] = sum_v Jreg[j,v]*shapedirs[v,c,l]; l==150 -> v_template ----------------
// grid 126 (v-chunks of 40), block 512 (453 active = 3*151). Coalesced sd reads, atomic accumulate.
__global__ void k_js(const float* __restrict__ jreg, const float* __restrict__ sd,
                     const float* __restrict__ vt, float* __restrict__ JS) {
  int t = threadIdx.x;
  if (t >= 453) return;
  int c = t / 151, l = t - c * 151;
  int v0 = blockIdx.x * 40;
  int v1 = v0 + 40; if (v1 > cV) v1 = cV;
  float acc[5] = {0.f, 0.f, 0.f, 0.f, 0.f};
  for (int v = v0; v < v1; ++v) {
    float x = (l < 150) ? sd[(size_t)(v * 3 + c) * 150 + l] : vt[v * 3 + c];
#pragma unroll
    for (int j = 0; j < 5; ++j)
      acc[j] = fmaf(jreg[j * cV + v], x, acc[j]);   // jreg read is wave-uniform -> scalar
  }
#pragma unroll
  for (int j = 0; j < 5; ++j)
    atomicAdd(&JS[(j * 3 + c) * 151 + l], acc[j]);
}

// ---------------- k_batch: per-batch joints, rot mats, kinematic chain, A_rel, pose_feature, y_rot ----------------
__global__ void k_batch(const float* __restrict__ shp, const float* __restrict__ expr,
                        const float* __restrict__ pose, const float* __restrict__ eyep,
                        const float* __restrict__ JS, float* __restrict__ Arel,
                        float* __restrict__ pf, int* __restrict__ yrot) {
  int b = blockIdx.x * 64 + threadIdx.x;
  if (b >= cB) return;
  // joints[j][c] = JS[j,c,150] + sum_l betas[l]*JS[j,c,l]
  float jnt[5][3];
#pragma unroll
  for (int j = 0; j < 5; ++j)
#pragma unroll
    for (int c = 0; c < 3; ++c)
      jnt[j][c] = JS[(j * 3 + c) * 151 + 150];
  for (int l = 0; l < 150; ++l) {
    float beta = (l < cS) ? shp[b * cS + l] : expr[b * cE + (l - cS)];
#pragma unroll
    for (int j = 0; j < 5; ++j)
#pragma unroll
      for (int c = 0; c < 3; ++c)
        jnt[j][c] = fmaf(beta, JS[(j * 3 + c) * 151 + l], jnt[j][c]);
  }
  // full_pose: [global, neck=0, jaw, eyeL, eyeR]
  float fp[5][3];
  fp[0][0] = pose[b * 6 + 0]; fp[0][1] = pose[b * 6 + 1]; fp[0][2] = pose[b * 6 + 2];
  fp[1][0] = 0.f; fp[1][1] = 0.f; fp[1][2] = 0.f;
  fp[2][0] = pose[b * 6 + 3]; fp[2][1] = pose[b * 6 + 4]; fp[2][2] = pose[b * 6 + 5];
  fp[3][0] = eyep[b * 6 + 0]; fp[3][1] = eyep[b * 6 + 1]; fp[3][2] = eyep[b * 6 + 2];
  fp[4][0] = eyep[b * 6 + 3]; fp[4][1] = eyep[b * 6 + 4]; fp[4][2] = eyep[b * 6 + 5];
  float R[5][9];
#pragma unroll
  for (int j = 0; j < 5; ++j) rodrigues9(fp[j][0], fp[j][1], fp[j][2], R[j]);
  // pose_feature = (R[1:] - I) row-major
#pragma unroll
  for (int j = 1; j < 5; ++j)
#pragma unroll
    for (int r = 0; r < 9; ++r) {
      float id = (r == 0 || r == 4 || r == 8) ? 1.f : 0.f;
      pf[b * 36 + (j - 1) * 9 + r] = R[j][r] - id;
    }
  // relative joints (PARENTS = [-1,0,1,1,1])
  float rel[5][3];
#pragma unroll
  for (int c = 0; c < 3; ++c) {
    rel[0][c] = jnt[0][c];
    rel[1][c] = jnt[1][c] - jnt[0][c];
    rel[2][c] = jnt[2][c] - jnt[1][c];
    rel[3][c] = jnt[3][c] - jnt[1][c];
    rel[4][c] = jnt[4][c] - jnt[1][c];
  }
  // kinematic chain G[j] = G[parent] @ T[j]
  float GR[5][9], Gt[5][3];
#pragma unroll
  for (int r = 0; r < 9; ++r) GR[0][r] = R[0][r];
#pragma unroll
  for (int c = 0; c < 3; ++c) Gt[0][c] = rel[0][c];
  const int par[5] = {0, 0, 1, 1, 1};
#pragma unroll
  for (int j = 1; j < 5; ++j) {
    int p = par[j];
#pragma unroll
    for (int r = 0; r < 3; ++r) {
#pragma unroll
      for (int cc = 0; cc < 3; ++cc)
        GR[j][r * 3 + cc] = GR[p][r * 3 + 0] * R[j][0 + cc] +
                            GR[p][r * 3 + 1] * R[j][3 + cc] +
                            GR[p][r * 3 + 2] * R[j][6 + cc];
      Gt[j][r] = Gt[p][r] + GR[p][r * 3 + 0] * rel[j][0] +
                            GR[p][r * 3 + 1] * rel[j][1] +
                            GR[p][r * 3 + 2] * rel[j][2];
    }
  }
  // A_rel rows (3x4 per joint): [R | t - R@joint]
#pragma unroll
  for (int j = 0; j < 5; ++j)
#pragma unroll
    for (int r = 0; r < 3; ++r) {
      float tj = Gt[j][r] - (GR[j][r * 3 + 0] * jnt[j][0] +
                             GR[j][r * 3 + 1] * jnt[j][1] +
                             GR[j][r * 3 + 2] * jnt[j][2]);
      Arel[b * 60 + j * 12 + r * 4 + 0] = GR[j][r * 3 + 0];
      Arel[b * 60 + j * 12 + r * 4 + 1] = GR[j][r * 3 + 1];
      Arel[b * 60 + j * 12 + r * 4 + 2] = GR[j][r * 3 + 2];
      Arel[b * 60 + j * 12 + r * 4 + 3] = tj;
    }
  // neck chain: rel_rot = R(aa[1]) @ R(aa[0]), aa = full_pose[[1,0]]
  float Ra[9], Rb[9];
  rodrigues9(fp[1][0], fp[1][1], fp[1][2], Ra);   // neck (zeros) ~ I
  rodrigues9(fp[0][0], fp[0][1], fp[0][2], Rb);   // global
  float r00 = Rb[0] * Ra[0] + Rb[1] * Ra[3] + Rb[2] * Ra[6];
  float r10 = Rb[3] * Ra[0] + Rb[4] * Ra[3] + Rb[5] * Ra[6];
  float r20 = Rb[6] * Ra[0] + Rb[7] * Ra[3] + Rb[8] * Ra[6];
  float sy = sqrtf(r00 * r00 + r10 * r10);
  float ydeg = atan2f(-r20, sy) * 57.29577951308232f;
  int y = (int)rintf(fminf(ydeg, 39.0f));          // rintf = round-half-even, matches jnp.round
  if (y < 0) y = (y < -39) ? 78 : (39 - y);
  yrot[b] = y;
}

// ---------------- k_at: AT[k][m] = combined A operand (betas ++ pose_feature), zero-padded to 192 ----------------
__global__ void k_at(const float* __restrict__ shp, const float* __restrict__ expr,
                     const float* __restrict__ pf, float* __restrict__ AT) {
  int id = blockIdx.x * 256 + threadIdx.x;  // 192*512 threads exactly
  int k = id >> 9, m = id & 511;
  float v;
  if (k < cS)       v = shp[m * cS + k];
  else if (k < cKS) v = expr[m * cE + (k - cS)];
  else if (k < cKT) v = pf[m * 36 + (k - cKS)];
  else              v = 0.f;
  AT[id] = v;
}

// ---------------- k_bt: BT[k][n] = shapedirs^T (k<150) ++ posedirs (150<=k<186), zero padded ----------------
__global__ void k_bt(const float* __restrict__ sd, const float* __restrict__ pd,
                     float* __restrict__ BT) {
  __shared__ float tile[32][33];
  const int tx = threadIdx.x;  // 32
  const int ty = threadIdx.y;  // 8
  const int nbase = blockIdx.x * 32;
  const int kbase = blockIdx.y * 32;
  const int k = kbase + tx;
#pragma unroll
  for (int i = 0; i < 4; ++i) {
    int n = nbase + ty + (i << 3);
    float v = 0.f;
    if (k < 150 && n < cV3) v = sd[(size_t)n * 150 + k];  // coalesced over tx
    tile[ty + (i << 3)][tx] = v;
  }
  __syncthreads();
#pragma unroll
  for (int i = 0; i < 4; ++i) {
    int kk = kbase + ty + (i << 3);
    int nn = nbase + tx;
    float v;
    if (kk < 150)      v = tile[tx][ty + (i << 3)];
    else if (kk < cKT) v = (nn < cV3) ? pd[(size_t)(kk - 150) * cV3 + nn] : 0.f;
    else               v = 0.f;
    BT[(size_t)kk * cNPAD + nn] = v;   // coalesced over tx
  }
}

// ---------------- k_main: fused GEMM (betas/pf x dirs) + v_template + LBS -> vertices ----------------
// grid (79, 8), block 256. Tile: 64 batches x 64 vertices (192 N cols). Micro: 4 batches x 4 vertices.
__global__ __launch_bounds__(256) void k_main(
    const float* __restrict__ BT, const float* __restrict__ AT,
    const float* __restrict__ Arel, const float* __restrict__ vtempl,
    const float* __restrict__ lbw, float* __restrict__ out) {
  __shared__ __align__(16) float smem[4096];   // As[16][64] + Bs[16][192] = 16 KB; reused for Arel tile
  float* As = smem;
  float* Bs = smem + 1024;
  const int t = threadIdx.x;
  const int tx = t & 15, ty = t >> 4;
  const int nbase = blockIdx.x * 192;
  const int mbase = blockIdx.y * 64;

  float acc[4][12];
#pragma unroll
  for (int m = 0; m < 4; ++m)
#pragma unroll
    for (int n = 0; n < 12; ++n) acc[m][n] = 0.f;

  const int ak = t >> 4;          // k row this thread stages for A
  const int ag = (t & 15) << 2;   // col group

#pragma unroll 1
  for (int kc = 0; kc < 12; ++kc) {
    const int krow = kc << 4;
    // global loads first (overlap with previous iteration's compute)
    float4 av = *(const float4*)(AT + (size_t)(krow + ak) * 512 + mbase + ag);
    float4 bv[3];
#pragma unroll
    for (int r = 0; r < 3; ++r) {
      int idx = t + (r << 8);
      int bk = idx / 48;
      int bc = (idx - bk * 48) << 2;
      bv[r] = *(const float4*)(BT + (size_t)(krow + bk) * cNPAD + nbase + bc);
    }
    __syncthreads();
    *(float4*)(As + ak * 64 + ag) = av;
#pragma unroll
    for (int r = 0; r < 3; ++r) {
      int idx = t + (r << 8);
      int bk = idx / 48;
      int bc = (idx - bk * 48) << 2;
      *(float4*)(Bs + bk * 192 + bc) = bv[r];
    }
    __syncthreads();
#pragma unroll
    for (int k = 0; k < 16; ++k) {
      float4 a4 = *(const float4*)(As + k * 64 + (ty << 2));
      float4 b0 = *(const float4*)(Bs + k * 192 + tx * 12);
      float4 b1 = *(const float4*)(Bs + k * 192 + tx * 12 + 4);
      float4 b2 = *(const float4*)(Bs + k * 192 + tx * 12 + 8);
      float aa[4]  = {a4.x, a4.y, a4.z, a4.w};
      float bb[12] = {b0.x, b0.y, b0.z, b0.w, b1.x, b1.y, b1.z, b1.w,
                      b2.x, b2.y, b2.z, b2.w};
#pragma unroll
      for (int m = 0; m < 4; ++m)
#pragma unroll
        for (int n = 0; n < 12; ++n)
          acc[m][n] = fmaf(aa[m], bb[n], acc[m][n]);
    }
  }
  __syncthreads();
  // stage A_rel tile: 64 batches x 60 floats = 3840 (fits in smem, coalesced)
  for (int i = t; i < 3840; i += 256)
    smem[i] = Arel[(size_t)mbase * 60 + i];
  __syncthreads();

  const int vbase = blockIdx.x * 64 + (tx << 2);
  float w[4][5], vtl[4][3];
#pragma unroll
  for (int vi = 0; vi < 4; ++vi) {
    int v = vbase + vi;
    bool ok = v < cV;
#pragma unroll
    for (int j = 0; j < 5; ++j) w[vi][j] = ok ? lbw[v * 5 + j] : 0.f;
#pragma unroll
    for (int c = 0; c < 3; ++c) vtl[vi][c] = ok ? vtempl[v * 3 + c] : 0.f;
  }
#pragma unroll
  for (int m = 0; m < 4; ++m) {
    const int bloc = (ty << 2) + m;
    const float* Ab = smem + bloc * 60;
    float p[4][3];
#pragma unroll
    for (int vi = 0; vi < 4; ++vi)
#pragma unroll
      for (int c = 0; c < 3; ++c)
        p[vi][c] = acc[m][vi * 3 + c] + vtl[vi][c];   // v_posed
    float o[4][3];
#pragma unroll
    for (int vi = 0; vi < 4; ++vi)
#pragma unroll
      for (int c = 0; c < 3; ++c) o[vi][c] = 0.f;
#pragma unroll
    for (int j = 0; j < 5; ++j) {
      float4 q0 = *(const float4*)(Ab + j * 12);       // A_rel row 0 (broadcast read)
      float4 q1 = *(const float4*)(Ab + j * 12 + 4);   // row 1
      float4 q2 = *(const float4*)(Ab + j * 12 + 8);   // row 2
#pragma unroll
      for (int vi = 0; vi < 4; ++vi) {
        float wj = w[vi][j];
        float s0 = q0.x * p[vi][0] + q0.y * p[vi][1] + q0.z * p[vi][2] + q0.w;
        float s1 = q1.x * p[vi][0] + q1.y * p[vi][1] + q1.z * p[vi][2] + q1.w;
        float s2 = q2.x * p[vi][0] + q2.y * p[vi][1] + q2.z * p[vi][2] + q2.w;
        o[vi][0] = fmaf(wj, s0, o[vi][0]);
        o[vi][1] = fmaf(wj, s1, o[vi][1]);
        o[vi][2] = fmaf(wj, s2, o[vi][2]);
      }
    }
    const int b = mbase + bloc;
#pragma unroll
    for (int vi = 0; vi < 4; ++vi) {
      int v = vbase + vi;
      if (v < cV) {
        size_t off = ((size_t)b * cV + v) * 3;
        out[off + 0] = o[vi][0];
        out[off + 1] = o[vi][1];
        out[off + 2] = o[vi][2];
      }
    }
  }
}

// ---------------- k_lmk: barycentric landmark gather (2d: dyn[yrot]++static, 3d: full) ----------------
__global__ void k_lmk(const float* __restrict__ verts, const int* __restrict__ faces,
                      const int* __restrict__ lmkf, const float* __restrict__ lmkb,
                      const int* __restrict__ dynf, const float* __restrict__ dynb,
                      const int* __restrict__ fullf, const float* __restrict__ fullb,
                      const int* __restrict__ yrot, float* __restrict__ out) {
  int id = blockIdx.x * 256 + threadIdx.x;
  if (id >= cB * cLF) return;
  int b = id / cLF, l = id - b * cLF;
  const float* vb = verts + (size_t)b * cV * 3;
  // landmarks2d
  {
    int f; float w0, w1, w2;
    if (l < cLD) {
      int yb = yrot[b];
      f = dynf[yb * cLD + l];
      const float* bp = dynb + ((size_t)yb * cLD + l) * 3;
      w0 = bp[0]; w1 = bp[1]; w2 = bp[2];
    } else {
      f = lmkf[l - cLD];
      const float* bp = lmkb + (size_t)(l - cLD) * 3;
      w0 = bp[0]; w1 = bp[1]; w2 = bp[2];
    }
    int i0 = faces[f * 3 + 0] * 3, i1 = faces[f * 3 + 1] * 3, i2 = faces[f * 3 + 2] * 3;
    size_t o = OUT_V + ((size_t)b * cLF + l) * 3;
    out[o + 0] = w0 * vb[i0 + 0] + w1 * vb[i1 + 0] + w2 * vb[i2 + 0];
    out[o + 1] = w0 * vb[i0 + 1] + w1 * vb[i1 + 1] + w2 * vb[i2 + 1];
    out[o + 2] = w0 * vb[i0 + 2] + w1 * vb[i1 + 2] + w2 * vb[i2 + 2];
  }
  // landmarks3d
  {
    int f = fullf[l];
    const float* bp = fullb + (size_t)l * 3;
    float w0 = bp[0], w1 = bp[1], w2 = bp[2];
    int i0 = faces[f * 3 + 0] * 3, i1 = faces[f * 3 + 1] * 3, i2 = faces[f * 3 + 2] * 3;
    size_t o = OUT_V + OUT_L + ((size_t)b * cLF + l) * 3;
    out[o + 0] = w0 * vb[i0 + 0] + w1 * vb[i1 + 0] + w2 * vb[i2 + 0];
    out[o + 1] = w0 * vb[i0 + 1] + w1 * vb[i1 + 1] + w2 * vb[i2 + 1];
    out[o + 2] = w0 * vb[i0 + 2] + w1 * vb[i1 + 2] + w2 * vb[i2 + 2];
  }
}

// ---------------- launch ----------------
extern "C" void kernel_launch(void* const* d_in, const int* in_sizes, int n_in,
                              void* d_out, int out_size, void* d_ws, size_t ws_size,
                              hipStream_t stream) {
  (void)in_sizes; (void)n_in; (void)out_size; (void)ws_size;
  const float* shp  = (const float*)d_in[0];
  const float* expr = (const float*)d_in[1];
  const float* pose = (const float*)d_in[2];
  const float* eyep = (const float*)d_in[3];
  const float* vt   = (const float*)d_in[4];
  const float* sd   = (const float*)d_in[5];
  const float* pd   = (const float*)d_in[6];
  const float* jreg = (const float*)d_in[7];
  const float* lbw  = (const float*)d_in[8];
  const int*   fcs  = (const int*)d_in[9];
  const int*   lmkf = (const int*)d_in[10];
  const float* lmkb = (const float*)d_in[11];
  const int*   dynf = (const int*)d_in[12];
  const float* dynb = (const float*)d_in[13];
  const int*   fullf= (const int*)d_in[14];
  const float* fullb= (const float*)d_in[15];
  float* out = (float*)d_out;
  float* ws  = (float*)d_ws;

  float* BT   = ws + WS_BT;
  float* AT   = ws + WS_AT;
  float* JS   = ws + WS_JS;
  float* Arel = ws + WS_AREL;
  float* pf   = ws + WS_PF;
  int*   yrot = (int*)(ws + WS_YROT);

  hipMemsetAsync(JS, 0, 2265 * sizeof(float), stream);
  k_js<<<126, 512, 0, stream>>>(jreg, sd, vt, JS);
  k_batch<<<8, 64, 0, stream>>>(shp, expr, pose, eyep, JS, Arel, pf, yrot);
  k_at<<<384, 256, 0, stream>>>(shp, expr, pf, AT);
  k_bt<<<dim3(474, 6), dim3(32, 8), 0, stream>>>(sd, pd, BT);
  k_main<<<dim3(79, 8), 256, 0, stream>>>(BT, AT, Arel, vt, lbw, out);
  k_lmk<<<136, 256, 0, stream>>>(out, fcs, lmkf, lmkb, dynf, dynb, fullf, fullb, yrot, out);
}

// Round 2
// 200.614 us; speedup vs baseline: 1.4667x; 1.4667x over previous
//
#include <hip/hip_runtime.h>
#include <cstddef>
#include <cstdint>

// ---------------- problem constants ----------------
#define cB   512
#define cV   5023
#define cS   100
#define cE   50
#define cJ   5
#define cLD  17
#define cLF  68

#define cV3    15069       // V*3
#define cNPAD  15072       // 157*96 padded N (rows of BTn)
#define cKPAD  192         // K padded (100+50+36 -> 192)

#define OUT_V  ((size_t)cB * cV * 3)
#define OUT_L  ((size_t)cB * cLF * 3)

// ws layout (float offsets; bf16 buffers are ushort-packed, 2 per float)
#define WS_BTN   ((size_t)0)                            // 15072*192 ushort = 1,446,912 floats
#define WS_ATM   (WS_BTN + (size_t)cNPAD * 96)          // 512*192 ushort = 49,152 floats
#define WS_JS    (WS_ATM + (size_t)cB * 96)             // 2272 floats
#define WS_AREL  (WS_JS + 2272)                         // 512*60
#define WS_PF    (WS_AREL + (size_t)cB * 60)            // 512*36
#define WS_YROT  (WS_PF + (size_t)cB * 36)              // 512 ints

typedef __attribute__((ext_vector_type(8))) short short8;
typedef __attribute__((ext_vector_type(4))) float f32x4;

// fp32 -> bf16 round-to-nearest-even
__device__ __forceinline__ unsigned short f2bf(float x) {
  unsigned int u = __float_as_uint(x);
  u = (u + 0x7fffu + ((u >> 16) & 1u)) >> 16;
  return (unsigned short)u;
}

// ---------------- rodrigues (matches jax reference in fp32) ----------------
__device__ __forceinline__ void rodrigues9(float rx, float ry, float rz, float* R) {
  float a0 = rx + 1e-8f, a1 = ry + 1e-8f, a2 = rz + 1e-8f;
  float angle = sqrtf(a0 * a0 + a1 * a1 + a2 * a2);
  float inv = 1.0f / angle;
  float x = rx * inv, y = ry * inv, z = rz * inv;
  float s = sinf(angle), c = cosf(angle);
  float t = 1.0f - c;
  float xy = x * y, xz = x * z, yz = y * z;
  R[0] = 1.0f - t * (y * y + z * z);
  R[1] = -s * z + t * xy;
  R[2] =  s * y + t * xz;
  R[3] =  s * z + t * xy;
  R[4] = 1.0f - t * (x * x + z * z);
  R[5] = -s * x + t * yz;
  R[6] = -s * y + t * xz;
  R[7] =  s * x + t * yz;
  R[8] = 1.0f - t * (x * x + y * y);
}

// ---------------- k_js: JS[j,c,l] = sum_v Jreg[j,v]*shapedirs[v,c,l]; l==150 -> v_template ----
__global__ void k_js(const float* __restrict__ jreg, const float* __restrict__ sd,
                     const float* __restrict__ vt, float* __restrict__ JS) {
  int t = threadIdx.x;
  if (t >= 453) return;
  int c = t / 151, l = t - c * 151;
  int v0 = blockIdx.x * 40;
  int v1 = v0 + 40; if (v1 > cV) v1 = cV;
  float acc[5] = {0.f, 0.f, 0.f, 0.f, 0.f};
  for (int v = v0; v < v1; ++v) {
    float x = (l < 150) ? sd[(size_t)(v * 3 + c) * 150 + l] : vt[v * 3 + c];
#pragma unroll
    for (int j = 0; j < 5; ++j)
      acc[j] = fmaf(jreg[j * cV + v], x, acc[j]);
  }
#pragma unroll
  for (int j = 0; j < 5; ++j)
    atomicAdd(&JS[(j * 3 + c) * 151 + l], acc[j]);
}

// ---------------- k_batch: joints, rot mats, chain, A_rel, pose_feature, y_rot ----------------
__global__ void k_batch(const float* __restrict__ shp, const float* __restrict__ expr,
                        const float* __restrict__ pose, const float* __restrict__ eyep,
                        const float* __restrict__ JSg, float* __restrict__ Arel,
                        float* __restrict__ pf, int* __restrict__ yrot) {
  __shared__ float js[2272];
  for (int i = threadIdx.x; i < 2265; i += 64) js[i] = JSg[i];
  __syncthreads();
  int b = blockIdx.x * 64 + threadIdx.x;
  if (b >= cB) return;
  float jnt[5][3];
#pragma unroll
  for (int j = 0; j < 5; ++j)
#pragma unroll
    for (int c = 0; c < 3; ++c)
      jnt[j][c] = js[(j * 3 + c) * 151 + 150];
  for (int l = 0; l < 150; ++l) {
    float beta = (l < cS) ? shp[b * cS + l] : expr[b * cE + (l - cS)];
#pragma unroll
    for (int j = 0; j < 5; ++j)
#pragma unroll
      for (int c = 0; c < 3; ++c)
        jnt[j][c] = fmaf(beta, js[(j * 3 + c) * 151 + l], jnt[j][c]);
  }
  float fp[5][3];
  fp[0][0] = pose[b * 6 + 0]; fp[0][1] = pose[b * 6 + 1]; fp[0][2] = pose[b * 6 + 2];
  fp[1][0] = 0.f; fp[1][1] = 0.f; fp[1][2] = 0.f;
  fp[2][0] = pose[b * 6 + 3]; fp[2][1] = pose[b * 6 + 4]; fp[2][2] = pose[b * 6 + 5];
  fp[3][0] = eyep[b * 6 + 0]; fp[3][1] = eyep[b * 6 + 1]; fp[3][2] = eyep[b * 6 + 2];
  fp[4][0] = eyep[b * 6 + 3]; fp[4][1] = eyep[b * 6 + 4]; fp[4][2] = eyep[b * 6 + 5];
  float R[5][9];
#pragma unroll
  for (int j = 0; j < 5; ++j) rodrigues9(fp[j][0], fp[j][1], fp[j][2], R[j]);
#pragma unroll
  for (int j = 1; j < 5; ++j)
#pragma unroll
    for (int r = 0; r < 9; ++r) {
      float id = (r == 0 || r == 4 || r == 8) ? 1.f : 0.f;
      pf[b * 36 + (j - 1) * 9 + r] = R[j][r] - id;
    }
  float rel[5][3];
#pragma unroll
  for (int c = 0; c < 3; ++c) {
    rel[0][c] = jnt[0][c];
    rel[1][c] = jnt[1][c] - jnt[0][c];
    rel[2][c] = jnt[2][c] - jnt[1][c];
    rel[3][c] = jnt[3][c] - jnt[1][c];
    rel[4][c] = jnt[4][c] - jnt[1][c];
  }
  float GR[5][9], Gt[5][3];
#pragma unroll
  for (int r = 0; r < 9; ++r) GR[0][r] = R[0][r];
#pragma unroll
  for (int c = 0; c < 3; ++c) Gt[0][c] = rel[0][c];
  const int par[5] = {0, 0, 1, 1, 1};
#pragma unroll
  for (int j = 1; j < 5; ++j) {
    int p = par[j];
#pragma unroll
    for (int r = 0; r < 3; ++r) {
#pragma unroll
      for (int cc = 0; cc < 3; ++cc)
        GR[j][r * 3 + cc] = GR[p][r * 3 + 0] * R[j][0 + cc] +
                            GR[p][r * 3 + 1] * R[j][3 + cc] +
                            GR[p][r * 3 + 2] * R[j][6 + cc];
      Gt[j][r] = Gt[p][r] + GR[p][r * 3 + 0] * rel[j][0] +
                            GR[p][r * 3 + 1] * rel[j][1] +
                            GR[p][r * 3 + 2] * rel[j][2];
    }
  }
#pragma unroll
  for (int j = 0; j < 5; ++j)
#pragma unroll
    for (int r = 0; r < 3; ++r) {
      float tj = Gt[j][r] - (GR[j][r * 3 + 0] * jnt[j][0] +
                             GR[j][r * 3 + 1] * jnt[j][1] +
                             GR[j][r * 3 + 2] * jnt[j][2]);
      Arel[b * 60 + j * 12 + r * 4 + 0] = GR[j][r * 3 + 0];
      Arel[b * 60 + j * 12 + r * 4 + 1] = GR[j][r * 3 + 1];
      Arel[b * 60 + j * 12 + r * 4 + 2] = GR[j][r * 3 + 2];
      Arel[b * 60 + j * 12 + r * 4 + 3] = tj;
    }
  float Ra[9], Rb[9];
  rodrigues9(fp[1][0], fp[1][1], fp[1][2], Ra);
  rodrigues9(fp[0][0], fp[0][1], fp[0][2], Rb);
  float r00 = Rb[0] * Ra[0] + Rb[1] * Ra[3] + Rb[2] * Ra[6];
  float r10 = Rb[3] * Ra[0] + Rb[4] * Ra[3] + Rb[5] * Ra[6];
  float r20 = Rb[6] * Ra[0] + Rb[7] * Ra[3] + Rb[8] * Ra[6];
  float sy = sqrtf(r00 * r00 + r10 * r10);
  float ydeg = atan2f(-r20, sy) * 57.29577951308232f;
  int y = (int)rintf(fminf(ydeg, 39.0f));
  if (y < 0) y = (y < -39) ? 78 : (39 - y);
  yrot[b] = y;
}

// ---------------- k_prep: build bf16 BTn[n][192] (sd part + zeros) and ATm[m][192] ----------------
// One thread = 4 consecutive k (one uint2 = 4 bf16 store). Grid covers BTn then ATm.
#define QB ((size_t)cNPAD * 48)    // 723,456 quads for BTn
__global__ void k_prep(const float* __restrict__ sd, const float* __restrict__ shp,
                       const float* __restrict__ expr, const float* __restrict__ pfm,
                       unsigned int* __restrict__ btn_u2, unsigned int* __restrict__ atm_u2) {
  size_t idx = (size_t)blockIdx.x * 256 + threadIdx.x;
  unsigned short o[4];
  if (idx < QB) {
    int n = (int)(idx / 48), kq = (int)(idx - (size_t)n * 48);
#pragma unroll
    for (int j = 0; j < 4; ++j) {
      int k = kq * 4 + j;
      float v = (n < cV3 && k < 150) ? sd[(size_t)n * 150 + k] : 0.f;
      o[j] = f2bf(v);
    }
    btn_u2[idx * 2 + 0] = (unsigned int)o[0] | ((unsigned int)o[1] << 16);
    btn_u2[idx * 2 + 1] = (unsigned int)o[2] | ((unsigned int)o[3] << 16);
  } else {
    size_t r = idx - QB;            // 512*48 quads for ATm
    int m = (int)(r / 48), kq = (int)(r - (size_t)m * 48);
#pragma unroll
    for (int j = 0; j < 4; ++j) {
      int k = kq * 4 + j;
      float v;
      if (k < cS)            v = shp[m * cS + k];
      else if (k < 150)      v = expr[m * cE + (k - cS)];
      else if (k < 186)      v = pfm[m * 36 + (k - 150)];
      else                   v = 0.f;
      o[j] = f2bf(v);
    }
    atm_u2[r * 2 + 0] = (unsigned int)o[0] | ((unsigned int)o[1] << 16);
    atm_u2[r * 2 + 1] = (unsigned int)o[2] | ((unsigned int)o[3] << 16);
  }
}

// ---------------- k_pdT: transpose posedirs (36 x V3) into BTn[:,150:186) bf16 ----------------
__global__ void k_pdT(const float* __restrict__ pd, unsigned int* __restrict__ btn_u) {
  __shared__ unsigned short T[64 * 36];
  const int t = threadIdx.x;
  const int n0 = blockIdx.x * 64;
#pragma unroll
  for (int it = 0; it < 9; ++it) {
    int e = t + it * 256;            // e < 2304 = 36*64
    int kk = e >> 6, ln = e & 63;
    int n = n0 + ln;
    float v = (n < cV3) ? pd[(size_t)kk * cV3 + n] : 0.f;
    T[ln * 36 + kk] = f2bf(v);
  }
  __syncthreads();
  // write 18 dwords (36 bf16) per row n
  for (int e = t; e < 64 * 18; e += 256) {
    int ln = e / 18, d = e - ln * 18;
    int n = n0 + ln;
    if (n < cV3) {
      unsigned int w = (unsigned int)T[ln * 36 + 2 * d] |
                       ((unsigned int)T[ln * 36 + 2 * d + 1] << 16);
      btn_u[(size_t)n * 96 + 75 + d] = w;   // 192 bf16 = 96 dwords/row; k=150 -> dword 75
    }
  }
}

// ---------------- k_main: MFMA bf16 GEMM (64b x 96n, K=192) + LBS epilogue ----------------
// block 256 (4 waves as 2m x 2n), grid (157 n-blocks, 8 m-blocks).
// LDS: As[64][200] + Bs[96][200] bf16 (64,000 B); epilogue reuses as P[96][68] f32 + Arel[64][60] f32.
__global__ __launch_bounds__(256) void k_main(
    const unsigned short* __restrict__ BTn, const unsigned short* __restrict__ ATm,
    const float* __restrict__ Arel, const float* __restrict__ vtempl,
    const float* __restrict__ lbw, float* __restrict__ out) {
  __shared__ __align__(16) unsigned short smem[32000];
  unsigned short* As = smem;                 // 64*200
  unsigned short* Bs = smem + 12800;         // 96*200
  float* Pf  = (float*)smem;                 // 96*68 f32 = 6528 floats
  float* ArL = ((float*)smem) + 6528;        // 64*60 = 3840 floats

  const int t  = threadIdx.x;
  const int nb = blockIdx.x, mb = blockIdx.y;

  // ---- stage A (64x192) and B (96x192) bf16 tiles; global reads fully coalesced ----
  {
    const unsigned short* bsrc = BTn + (size_t)nb * 96 * 192;   // contiguous 36,864 B
    const unsigned short* asrc = ATm + (size_t)mb * 64 * 192;   // contiguous 24,576 B
#pragma unroll
    for (int it = 0; it < 15; ++it) {
      int e = t + it * 256;                  // e < 3840 16-byte units
      uint4 val;
      int row, col;
      if (e < 2304) {                        // B: 96 rows * 24 units
        row = e / 24; col = e - row * 24;
        val = *(const uint4*)(bsrc + (size_t)e * 8);
        *(uint4*)(Bs + row * 200 + col * 8) = val;
      } else {
        int e2 = e - 2304;                   // A: 64 rows * 24 units
        row = e2 / 24; col = e2 - row * 24;
        val = *(const uint4*)(asrc + (size_t)e2 * 8);
        *(uint4*)(As + row * 200 + col * 8) = val;
      }
    }
  }
  __syncthreads();

  // ---- MFMA: wave w -> (wm = w>>1)*32 rows of M, (wn = w&1)*48 cols of N ----
  const int w = t >> 6, L = t & 63;
  const int wm = w >> 1, wn = w & 1;
  const int lr = L & 15, lq = L >> 4;

  f32x4 acc[2][3];
#pragma unroll
  for (int mt = 0; mt < 2; ++mt)
#pragma unroll
    for (int nt = 0; nt < 3; ++nt) acc[mt][nt] = (f32x4){0.f, 0.f, 0.f, 0.f};

#pragma unroll
  for (int ks = 0; ks < 6; ++ks) {
    const int ko = ks * 32 + lq * 8;
    short8 af[2], bf[3];
#pragma unroll
    for (int mt = 0; mt < 2; ++mt)
      af[mt] = *(const short8*)(As + (wm * 32 + mt * 16 + lr) * 200 + ko);
#pragma unroll
    for (int nt = 0; nt < 3; ++nt)
      bf[nt] = *(const short8*)(Bs + (wn * 48 + nt * 16 + lr) * 200 + ko);
#pragma unroll
    for (int mt = 0; mt < 2; ++mt)
#pragma unroll
      for (int nt = 0; nt < 3; ++nt)
        acc[mt][nt] = __builtin_amdgcn_mfma_f32_16x16x32_bf16(af[mt], bf[nt], acc[mt][nt], 0, 0, 0);
  }
  __syncthreads();   // all frag reads done; safe to overwrite LDS

  // ---- store acc to LDS as P[n_loc][m_loc] (pad 68), and stage Arel tile ----
#pragma unroll
  for (int mt = 0; mt < 2; ++mt)
#pragma unroll
    for (int nt = 0; nt < 3; ++nt) {
      int m_base = wm * 32 + mt * 16 + lq * 4;       // 4 consecutive m in regs
      int n_loc  = wn * 48 + nt * 16 + lr;
      *(f32x4*)(Pf + n_loc * 68 + m_base) = acc[mt][nt];
    }
  for (int e = t; e < 3840; e += 256)
    ArL[e] = Arel[(size_t)mb * 64 * 60 + e];
  __syncthreads();

  // ---- LBS epilogue: thread = (v_loc = t&31, bgrp = t>>5), loops 8 batches ----
  const int v_loc = t & 31, bgrp = t >> 5;
  const int v = nb * 32 + v_loc;
  float wj[5], vtl[3];
  const bool vok = (v < cV);
#pragma unroll
  for (int j = 0; j < 5; ++j) wj[j] = vok ? lbw[v * 5 + j] : 0.f;
#pragma unroll
  for (int c = 0; c < 3; ++c) vtl[c] = vok ? vtempl[v * 3 + c] : 0.f;

#pragma unroll
  for (int i = 0; i < 8; ++i) {
    const int b_loc = bgrp * 8 + i;
    const float* q = ArL + b_loc * 60;
    float px = Pf[(v_loc * 3 + 0) * 68 + b_loc] + vtl[0];
    float py = Pf[(v_loc * 3 + 1) * 68 + b_loc] + vtl[1];
    float pz = Pf[(v_loc * 3 + 2) * 68 + b_loc] + vtl[2];
    float o0 = 0.f, o1 = 0.f, o2 = 0.f;
#pragma unroll
    for (int j = 0; j < 5; ++j) {
      f32x4 q0 = *(const f32x4*)(q + j * 12);
      f32x4 q1 = *(const f32x4*)(q + j * 12 + 4);
      f32x4 q2 = *(const f32x4*)(q + j * 12 + 8);
      float s0 = q0.x * px + q0.y * py + q0.z * pz + q0.w;
      float s1 = q1.x * px + q1.y * py + q1.z * pz + q1.w;
      float s2 = q2.x * px + q2.y * py + q2.z * pz + q2.w;
      o0 = fmaf(wj[j], s0, o0);
      o1 = fmaf(wj[j], s1, o1);
      o2 = fmaf(wj[j], s2, o2);
    }
    if (vok) {
      const int b = mb * 64 + b_loc;
      size_t off = ((size_t)b * cV + v) * 3;
      out[off + 0] = o0;
      out[off + 1] = o1;
      out[off + 2] = o2;
    }
  }
}

// ---------------- k_lmk: barycentric landmark gather ----------------
__global__ void k_lmk(const float* __restrict__ verts, const int* __restrict__ faces,
                      const int* __restrict__ lmkf, const float* __restrict__ lmkb,
                      const int* __restrict__ dynf, const float* __restrict__ dynb,
                      const int* __restrict__ fullf, const float* __restrict__ fullb,
                      const int* __restrict__ yrot, float* __restrict__ out) {
  int id = blockIdx.x * 256 + threadIdx.x;
  if (id >= cB * cLF) return;
  int b = id / cLF, l = id - b * cLF;
  const float* vb = verts + (size_t)b * cV * 3;
  {
    int f; float w0, w1, w2;
    if (l < cLD) {
      int yb = yrot[b];
      f = dynf[yb * cLD + l];
      const float* bp = dynb + ((size_t)yb * cLD + l) * 3;
      w0 = bp[0]; w1 = bp[1]; w2 = bp[2];
    } else {
      f = lmkf[l - cLD];
      const float* bp = lmkb + (size_t)(l - cLD) * 3;
      w0 = bp[0]; w1 = bp[1]; w2 = bp[2];
    }
    int i0 = faces[f * 3 + 0] * 3, i1 = faces[f * 3 + 1] * 3, i2 = faces[f * 3 + 2] * 3;
    size_t o = OUT_V + ((size_t)b * cLF + l) * 3;
    out[o + 0] = w0 * vb[i0 + 0] + w1 * vb[i1 + 0] + w2 * vb[i2 + 0];
    out[o + 1] = w0 * vb[i0 + 1] + w1 * vb[i1 + 1] + w2 * vb[i2 + 1];
    out[o + 2] = w0 * vb[i0 + 2] + w1 * vb[i1 + 2] + w2 * vb[i2 + 2];
  }
  {
    int f = fullf[l];
    const float* bp = fullb + (size_t)l * 3;
    float w0 = bp[0], w1 = bp[1], w2 = bp[2];
    int i0 = faces[f * 3 + 0] * 3, i1 = faces[f * 3 + 1] * 3, i2 = faces[f * 3 + 2] * 3;
    size_t o = OUT_V + OUT_L + ((size_t)b * cLF + l) * 3;
    out[o + 0] = w0 * vb[i0 + 0] + w1 * vb[i1 + 0] + w2 * vb[i2 + 0];
    out[o + 1] = w0 * vb[i0 + 1] + w1 * vb[i1 + 1] + w2 * vb[i2 + 1];
    out[o + 2] = w0 * vb[i0 + 2] + w1 * vb[i1 + 2] + w2 * vb[i2 + 2];
  }
}

// ---------------- launch ----------------
extern "C" void kernel_launch(void* const* d_in, const int* in_sizes, int n_in,
                              void* d_out, int out_size, void* d_ws, size_t ws_size,
                              hipStream_t stream) {
  (void)in_sizes; (void)n_in; (void)out_size; (void)ws_size;
  const float* shp  = (const float*)d_in[0];
  const float* expr = (const float*)d_in[1];
  const float* pose = (const float*)d_in[2];
  const float* eyep = (const float*)d_in[3];
  const float* vt   = (const float*)d_in[4];
  const float* sd   = (const float*)d_in[5];
  const float* pd   = (const float*)d_in[6];
  const float* jreg = (const float*)d_in[7];
  const float* lbw  = (const float*)d_in[8];
  const int*   fcs  = (const int*)d_in[9];
  const int*   lmkf = (const int*)d_in[10];
  const float* lmkb = (const float*)d_in[11];
  const int*   dynf = (const int*)d_in[12];
  const float* dynb = (const float*)d_in[13];
  const int*   fullf= (const int*)d_in[14];
  const float* fullb= (const float*)d_in[15];
  float* out = (float*)d_out;
  float* ws  = (float*)d_ws;

  unsigned short* BTn = (unsigned short*)(ws + WS_BTN);
  unsigned short* ATm = (unsigned short*)(ws + WS_ATM);
  float* JS   = ws + WS_JS;
  float* Arel = ws + WS_AREL;
  float* pf   = ws + WS_PF;
  int*   yrot = (int*)(ws + WS_YROT);

  hipMemsetAsync(JS, 0, 2272 * sizeof(float), stream);
  k_js<<<126, 512, 0, stream>>>(jreg, sd, vt, JS);
  k_batch<<<8, 64, 0, stream>>>(shp, expr, pose, eyep, JS, Arel, pf, yrot);
  k_prep<<<2922, 256, 0, stream>>>(sd, shp, expr, pf,
                                   (unsigned int*)BTn, (unsigned int*)ATm);
  k_pdT<<<236, 256, 0, stream>>>(pd, (unsigned int*)BTn);
  k_main<<<dim3(157, 8), 256, 0, stream>>>(BTn, ATm, Arel, vt, lbw, out);
  k_lmk<<<136, 256, 0, stream>>>(out, fcs, lmkf, lmkb, dynf, dynb, fullf, fullb, yrot, out);
}